// Round 9
// baseline (3480.974 us; speedup 1.0000x reference)
//
#include <hip/hip_runtime.h>
#include <hip/hip_fp16.h>

typedef unsigned int  u32;
typedef unsigned short u16;

typedef _Float16 h2v __attribute__((ext_vector_type(2)));
typedef _Float16 h8v __attribute__((ext_vector_type(8)));
typedef float    f4v __attribute__((ext_vector_type(4)));

// ---------- helpers ----------
static __device__ __forceinline__ u16 f2h_bits(float x){
    _Float16 h = (_Float16)x;
    return __builtin_bit_cast(u16, h);
}
static __device__ __forceinline__ u32 pack2(float a, float b){
    return (u32)f2h_bits(a) | ((u32)f2h_bits(b) << 16);
}
static __device__ __forceinline__ float h2f(u16 b){
    return (float)__builtin_bit_cast(_Float16, b);
}
// quad-perm cross-lane via DPP (VALU, not DS pipe). xor1 = 0xB1, xor2 = 0x4E.
template<int CTRL>
static __device__ __forceinline__ float dpp_qp(float x){
#if __has_builtin(__builtin_amdgcn_mov_dpp)
    int r = __builtin_amdgcn_mov_dpp(__builtin_bit_cast(int, x), CTRL, 0xF, 0xF, true);
    return __builtin_bit_cast(float, r);
#else
    return __shfl_xor(x, (CTRL == 0xB1) ? 1 : 2);
#endif
}

// B=128, T=512, D=H=256, 4H=1024; beta in [0,256): beta<128 -> input1, else input2
// Slot s = 4j+q owns gate row r(s) = (s&3)*256 + (s>>2)  (i,f,g,o of elem j).

// ---------- kernel: convert weights ----------
// wih16 : [l][g][d] fp16 (flat cast, NORMAL order - proj B operand)
// wmf   : [l][w][nf][kf][lane] uint4 MFMA B-frags of Whh (slot-permuted rows):
//         lane l holds Whh[r(s)][k..k+7], s = w*128+nf*16+(l&15), k = kf*32+(l>>4)*8
// biasP : [l][slot] = (b_ih+b_hh)[r(slot)]  (added in proj epilogue)
__global__ void cvt_weights(const float* __restrict__ Wih,
                            const float* __restrict__ Whh,
                            const float* __restrict__ bih,
                            const float* __restrict__ bhh,
                            u32* __restrict__ wih16u,   // 262144 u32
                            u32* __restrict__ wmf32,    // 262144 u32 (2 layers x 512KB)
                            float* __restrict__ biasP){ // 2048
    u32 e = blockIdx.x * blockDim.x + threadIdx.x;      // 0 .. 262143
    {
        float2 v = ((const float2*)Wih)[e];
        wih16u[e] = pack2(v.x, v.y);
    }
    {
        u32 l = e >> 17, rem = e & 131071u;
        u32 w = rem >> 14, nf = (rem >> 11) & 7u, kf = (rem >> 8) & 7u;
        u32 lane = (rem >> 2) & 63u, word = rem & 3u;
        u32 s = w*128u + nf*16u + (lane & 15u);
        u32 r = (s & 3u)*256u + (s >> 2);
        u32 k = kf*32u + (lane >> 4)*8u + word*2u;
        float2 v = ((const float2*)Whh)[((size_t)(l*1024u + r))*128u + (k >> 1)];
        wmf32[e] = pack2(v.x, v.y);
    }
    if (e < 2048u){
        u32 l = e >> 10, Ls = e & 1023u;
        u32 src = l*1024u + (((Ls & 3u) << 8) | (Ls >> 2));
        biasP[e] = bih[src] + bhh[src];
    }
}

// ---------- per-chunk input convert: fp32 -> fp16 rows [beta][tc][256] ----------
__global__ void cvt_chunk(const float* __restrict__ in1,
                          const float* __restrict__ in2,
                          u16* __restrict__ a16,    // [256*Tc][256] fp16
                          int t0, int lgTc){
    u32 idx = blockIdx.x * blockDim.x + threadIdx.x;   // float4 units
    u32 c4  = idx & 63;
    u32 row = idx >> 6;
    u32 tc   = row & ((1u << lgTc) - 1u);
    u32 beta = row >> lgTc;
    const float* base = (beta < 128u) ? in1 : in2;
    float4 v = *(const float4*)(base + ((size_t)(beta & 127u)*512u + (size_t)(t0 + tc))*256u + c4*4u);
    ((uint2*)a16)[idx] = make_uint2(pack2(v.x, v.y), pack2(v.z, v.w));
}

// ---------- projection GEMM:  C[Mc,1024] = A[Mc,256] * B[1024,256]^T + bias ----------
// A fp16 [Mc][256], B staged in LDS (66KB -> 2 wg/CU). grid = (Mtiles, 8 Ntiles).
// Output columns stored PERMUTED: col n -> slot ((n&255)<<2)|(n>>8); bias added here.
__global__ __launch_bounds__(256) void proj_gemm(
        const u16*  __restrict__ A16,     // [Mc][256] fp16
        const u16*  __restrict__ Bw,      // [1024][256] fp16 = W_ih[l]
        const float* __restrict__ biasP,  // [1024] permuted, this layer
        u16*        __restrict__ Cout){   // [Mc][1024] fp16 (permuted cols)
    __shared__ u16 Blds[128][264];        // 528B rows: 16B-aligned for uint4
    const int tid = threadIdx.x;
    const int m0 = blockIdx.x * 128;
    const int n0 = blockIdx.y * 128;

    {   // stage B tile: 128 rows x 32 uint4, coalesced 16B loads
        const uint4* src = (const uint4*)Bw;
        #pragma unroll
        for (int i = 0; i < 16; i++){
            int idx = i*256 + tid;          // 0..4095
            int r = idx >> 5, c4 = idx & 31;
            uint4 v = src[(size_t)(n0 + r)*32 + c4];
            *(uint4*)&Blds[r][c4*8] = v;
        }
    }
    __syncthreads();

    const int l   = tid & 63;
    const int wid = tid >> 6;
    const int wm = (wid >> 1) * 64;
    const int wn = (wid & 1) * 64;
    const int lr = l & 15;
    const int lk = l >> 4;

    f4v acc[4][4] = {};

    const u16* a16p[4];
    #pragma unroll
    for (int f = 0; f < 4; f++)
        a16p[f] = A16 + (size_t)(m0 + wm + f*16 + lr)*256 + lk*8;

    #pragma unroll
    for (int ks = 0; ks < 8; ks++){
        uint4 a_[4], b_[4];
        #pragma unroll
        for (int f = 0; f < 4; f++)
            a_[f] = *(const uint4*)(a16p[f] + ks*32);
        #pragma unroll
        for (int f = 0; f < 4; f++)
            b_[f] = *(const uint4*)&Blds[wn + f*16 + lr][ks*32 + lk*8];
        #pragma unroll
        for (int fm = 0; fm < 4; fm++)
            #pragma unroll
            for (int fn = 0; fn < 4; fn++)
                acc[fm][fn] = __builtin_amdgcn_mfma_f32_16x16x32_f16(
                    __builtin_bit_cast(h8v, a_[fm]),
                    __builtin_bit_cast(h8v, b_[fn]),
                    acc[fm][fn], 0, 0, 0);
    }

    // D[row = 4*lk + i][col = lr]; store col n at permuted slot, + bias
    int np_[4]; float bv_[4];
    #pragma unroll
    for (int fn = 0; fn < 4; fn++){
        int n = n0 + wn + fn*16 + lr;
        np_[fn] = ((n & 255) << 2) | (n >> 8);
        bv_[fn] = biasP[np_[fn]];
    }
    #pragma unroll
    for (int fm = 0; fm < 4; fm++){
        #pragma unroll
        for (int i = 0; i < 4; i++){
            int m = m0 + wm + fm*16 + lk*4 + i;
            size_t rowoff = (size_t)m*1024;
            #pragma unroll
            for (int fn = 0; fn < 4; fn++)
                Cout[rowoff + np_[fn]] = f2h_bits(acc[fm][fn][i] + bv_[fn]);
        }
    }
}

// ---------- MFMA LSTM recurrence over one T-chunk ----------
// 256 wgs (1 beta each) x 512 threads (8 waves). Wave w owns slots
// [w*128, w*128+128) = 8 N-frags. A-operand = h broadcast to all 16 MFMA rows
// (rows replicated -> every lane's acc[.][0] holds gate at col=lr).
// Whh: kf 0..5 in 192 VGPR/lane, kf 6..7 in 128KB LDS. One barrier/step.
__global__ __launch_bounds__(512, 2) void mfma_rec(
        const u16* __restrict__ xg,      // [beta][tc][1024] fp16 (bias included)
        const uint4* __restrict__ wmf,   // [8][8][8][64] uint4, this layer
        u16* __restrict__ hseq,          // [beta][tc][256] chunk, or null
        u16* __restrict__ h_state,       // [256][256] fp16
        float* __restrict__ c_state,     // [256][256] f32
        int Tc, int write_seq, int first){
    __shared__ uint4 blds[8192];                 // 128 KB: kf 6,7 B-frags
    __shared__ alignas(16) u16 hbuf[2][256];     // h double buffer
    __shared__ alignas(16) u16 xbuf[2][1024];    // xg double buffer

    const int tid = threadIdx.x;
    const int w  = tid >> 6, l = tid & 63;
    const int lr = l & 15,  lk = l >> 4;
    const int q  = lr & 3;
    const int beta = blockIdx.x;

    // B: kf 0..5 resident in VGPRs (48 x uint4 = 192 regs)
    uint4 wB[8][6];
    #pragma unroll
    for (int nf = 0; nf < 8; nf++)
        #pragma unroll
        for (int kf = 0; kf < 6; kf++)
            wB[nf][kf] = wmf[((w*8+nf)*8 + kf)*64 + l];
    // B: kf 6,7 staged to LDS (each thread copies 16 uint4)
    #pragma unroll
    for (int i = 0; i < 16; i++){
        int d = i*512 + tid;                 // 0..8191
        int lane = d & 63, frag = d >> 6;    // frag = (ww*8+nff)*2 + kfi
        int kfi = frag & 1, nff = (frag >> 1) & 7, ww = frag >> 4;
        blds[d] = wmf[((ww*8+nff)*8 + 6+kfi)*64 + lane];
    }

    // init c (valid on q==0 lanes; others garbage-but-unused)
    float cc[8];
    #pragma unroll
    for (int nf = 0; nf < 8; nf++){
        int j = (w*8+nf)*4 + (lr >> 2);
        cc[nf] = first ? 0.f : c_state[(size_t)beta*256 + j];
    }
    // init h buffer + stage xg for tc=0
    if (tid < 32){
        uint4 hv = first ? make_uint4(0,0,0,0)
                         : *(const uint4*)(h_state + (size_t)beta*256 + tid*8);
        *(uint4*)&hbuf[0][tid*8] = hv;
    }
    const u16* xgb = xg + ((size_t)beta * Tc) * 1024;
    if (tid < 128)
        *(uint4*)&xbuf[0][tid*8] = *(const uint4*)(xgb + tid*8);
    __syncthreads();

    for (int tc = 0; tc < Tc; tc++){
        const int cur = tc & 1, nxt = cur ^ 1;

        // stage next step's xg (consumed next iter; latency hidden by MFMA)
        if (tid < 128){
            int stc = (tc + 1 < Tc) ? tc + 1 : tc;
            *(uint4*)&xbuf[nxt][tid*8] =
                *(const uint4*)(xgb + (size_t)stc*1024 + tid*8);
        }

        #pragma unroll
        for (int pass = 0; pass < 2; pass++){
            f4v acc[4] = {};
            #pragma unroll
            for (int kf = 0; kf < 8; kf++){
                uint4 av = *(const uint4*)&hbuf[cur][kf*32 + lk*8];  // broadcast
                #pragma unroll
                for (int f = 0; f < 4; f++){
                    const int nf = pass*4 + f;
                    uint4 bv = (kf < 6) ? wB[nf][kf]
                                        : blds[((w*8+nf)*2 + (kf-6))*64 + l];
                    acc[f] = __builtin_amdgcn_mfma_f32_16x16x32_f16(
                        __builtin_bit_cast(h8v, av),
                        __builtin_bit_cast(h8v, bv),
                        acc[f], 0, 0, 0);
                }
            }
            #pragma unroll
            for (int f = 0; f < 4; f++){
                const int nf = pass*4 + f;
                float val = acc[f][0] + h2f(xbuf[cur][w*128 + nf*16 + lr]);
                // activation: q==2 -> tanh, else sigmoid
                float targ = (q == 2) ? 2.f*val : -val;
                float e1 = __expf(targ);
                float rr = 1.f / (1.f + e1);
                float a  = (q == 2) ? 1.f - 2.f*rr : rr;
                // quad DPP: on q==0 lane, a=i p1=f p2=g p3=o (r5-validated)
                float p1 = dpp_qp<0xB1>(a);
                float p2 = dpp_qp<0x4E>(a);
                float p3 = dpp_qp<0x4E>(p1);
                float cn = p1*cc[nf] + a*p2;
                cc[nf] = cn;
                float e2 = __expf(2.f*cn);
                float th = 1.f - 2.f/(e2 + 1.f);
                float h  = p3 * th;
                if ((l & 51) == 0)   // lk==0 && lr in {0,4,8,12}
                    hbuf[nxt][(w*8+nf)*4 + (l >> 2)] = f2h_bits(h);
            }
        }
        __syncthreads();

        if (write_seq && tid < 32){
            uint4 hv = *(const uint4*)&hbuf[nxt][tid*8];
            *(uint4*)(hseq + ((size_t)beta*Tc + tc)*256 + tid*8) = hv;
        }
    }

    if (tid < 32)
        *(uint4*)(h_state + (size_t)beta*256 + tid*8) =
            *(const uint4*)&hbuf[Tc & 1][tid*8];
    if ((l & 51) == 0){
        #pragma unroll
        for (int nf = 0; nf < 8; nf++)
            c_state[(size_t)beta*256 + (w*8+nf)*4 + (l >> 2)] = cc[nf];
    }
}

// ---------- final FC: out[r][k] = relu(hn[r]) . fc_w[k] + fc_b[k] ----------
__global__ void fc_out(const u16* __restrict__ hlast,
                       const float* __restrict__ fcw,   // [5][256]
                       const float* __restrict__ fcb,   // [5]
                       float* __restrict__ out){        // [512][5]
    int r = blockIdx.x;
    int lane = threadIdx.x;      // 0..63
    int inp = r >> 8, rem = r & 255, l = rem >> 7, b = rem & 127;
    int beta = inp*128 + b;
    const u16* h = hlast + ((size_t)l*256 + beta)*256;

    int j0 = lane * 4;
    uint2 hb = *(const uint2*)(h + j0);
    h2v p0 = __builtin_bit_cast(h2v, hb.x), p1 = __builtin_bit_cast(h2v, hb.y);
    float hv0 = fmaxf((float)p0[0], 0.f);
    float hv1 = fmaxf((float)p0[1], 0.f);
    float hv2 = fmaxf((float)p1[0], 0.f);
    float hv3 = fmaxf((float)p1[1], 0.f);

    float acc[5];
    #pragma unroll
    for (int k = 0; k < 5; k++){
        float4 w = *(const float4*)(fcw + k*256 + j0);
        acc[k] = hv0*w.x + hv1*w.y + hv2*w.z + hv3*w.w;
    }
    #pragma unroll
    for (int k = 0; k < 5; k++)
        #pragma unroll
        for (int off = 32; off > 0; off >>= 1)
            acc[k] += __shfl_xor(acc[k], off);
    if (lane == 0){
        #pragma unroll
        for (int k = 0; k < 5; k++)
            out[(size_t)r*5 + k] = acc[k] + fcb[k];
    }
}

// ---------- host launch ----------
extern "C" void kernel_launch(void* const* d_in, const int* in_sizes, int n_in,
                              void* d_out, int out_size, void* d_ws, size_t ws_size,
                              hipStream_t stream) {
    const float* in1 = (const float*)d_in[0];
    const float* in2 = (const float*)d_in[1];
    const float* Wih = (const float*)d_in[2];
    const float* Whh = (const float*)d_in[3];
    const float* bih = (const float*)d_in[4];
    const float* bhh = (const float*)d_in[5];
    const float* fcw = (const float*)d_in[6];
    const float* fcb = (const float*)d_in[7];
    float* out = (float*)d_out;

    // fixed workspace region (~3 MB)
    char* ws = (char*)d_ws;
    u16*   wih16   = (u16*)  (ws + 0x000000);   // [2][1024][256] fp16 (1 MB)
    u32*   wmf32   = (u32*)  (ws + 0x100000);   // [2][32768] uint4     (1 MB)
    float* biasP   = (float*)(ws + 0x200000);   // [2][1024]
    u16*   h_state = (u16*)  (ws + 0x202000);   // [2][256][256] fp16 (256 KB)
    float* c_state = (float*)(ws + 0x242000);   // [2][256][256] f32  (512 KB)
    const size_t chunk_off = 0x300000;

    // adaptive T-chunk: xg chunk = Tc*512KB, hsc chunk (a16/hseq alias) = Tc*128KB
    int Tc = 8;
    for (int cand = 512; cand >= 8; cand >>= 1){
        if (chunk_off + (size_t)cand * 655360ull <= ws_size){ Tc = cand; break; }
    }
    int lgTc = 31 - __builtin_clz((u32)Tc);
    u16* xgc = (u16*)(ws + chunk_off);
    u16* hsc = (u16*)(ws + chunk_off + (size_t)Tc * 524288ull);  // dual: a16 then hseq

    cvt_weights<<<1024, 256, 0, stream>>>(Wih, Whh, bih, bhh,
                                          (u32*)wih16, wmf32, biasP);

    const int nch = 512 / Tc;
    dim3 pg(2*Tc, 8);   // x = M-tiles (wgid%8 = mtile%8 -> XCD A-locality)
    const uint4* wmf = (const uint4*)wmf32;
    for (int k = 0; k < nch; k++){
        int t0 = k * Tc;
        // convert this chunk's fp32 inputs -> fp16 A (into hsc, dead after proj0)
        cvt_chunk<<<64*Tc, 256, 0, stream>>>(in1, in2, hsc, t0, lgTc);
        // layer 0
        proj_gemm<<<pg, 256, 0, stream>>>(hsc, wih16, biasP, xgc);
        mfma_rec<<<256, 512, 0, stream>>>((const u16*)xgc, wmf,
                                          hsc, h_state, c_state,
                                          Tc, 1, k == 0);
        // layer 1
        proj_gemm<<<pg, 256, 0, stream>>>(hsc, wih16 + 262144, biasP + 1024, xgc);
        mfma_rec<<<256, 512, 0, stream>>>((const u16*)xgc, wmf + 32768,
                                          (u16*)nullptr, h_state + 65536, c_state + 65536,
                                          Tc, 0, k == 0);
    }
    fc_out<<<512, 64, 0, stream>>>(h_state, fcw, fcb, out);
}

// Round 10
// 2286.623 us; speedup vs baseline: 1.5223x; 1.5223x over previous
//
#include <hip/hip_runtime.h>
#include <hip/hip_fp16.h>

typedef unsigned int  u32;
typedef unsigned short u16;

typedef _Float16 h2v __attribute__((ext_vector_type(2)));
typedef _Float16 h8v __attribute__((ext_vector_type(8)));
typedef float    f4v __attribute__((ext_vector_type(4)));

// ---------- helpers ----------
static __device__ __forceinline__ u16 f2h_bits(float x){
    _Float16 h = (_Float16)x;
    return __builtin_bit_cast(u16, h);
}
static __device__ __forceinline__ u32 pack2(float a, float b){
    return (u32)f2h_bits(a) | ((u32)f2h_bits(b) << 16);
}
static __device__ __forceinline__ float fdot2(u32 w, u32 h, float acc){
#if __has_builtin(__builtin_amdgcn_fdot2)
    return __builtin_amdgcn_fdot2(__builtin_bit_cast(h2v, w),
                                  __builtin_bit_cast(h2v, h), acc, false);
#else
    h2v wv = __builtin_bit_cast(h2v, w), hv = __builtin_bit_cast(h2v, h);
    return acc + (float)wv[0]*(float)hv[0] + (float)wv[1]*(float)hv[1];
#endif
}
// quad-perm cross-lane via DPP (VALU, not DS pipe). xor1 = 0xB1, xor2 = 0x4E.
template<int CTRL>
static __device__ __forceinline__ float dpp_qp(float x){
#if __has_builtin(__builtin_amdgcn_mov_dpp)
    int r = __builtin_amdgcn_mov_dpp(__builtin_bit_cast(int, x), CTRL, 0xF, 0xF, true);
    return __builtin_bit_cast(float, r);
#else
    return __shfl_xor(x, (CTRL == 0xB1) ? 1 : 2);
#endif
}

// B=128, T=512, D=H=256, 4H=1024; beta in [0,256): beta<128 -> input1, else input2
// Slot L = 4j+q : quad j owns gate rows {q*256+j, q=0..3} (i,f,g,o of elem j).
// k-split: thread (j,q) computes PARTIAL dots of all 4 rows over k in [64q,64q+64).

// ---------- kernel: convert weights ----------
__global__ void cvt_weights(const float* __restrict__ Wih,
                            const float* __restrict__ Whh,
                            const float* __restrict__ bih,
                            const float* __restrict__ bhh,
                            u32* __restrict__ wih16u,   // 262144 u32
                            u32* __restrict__ wreg,     // 196608 u32
                            u32* __restrict__ wldsg,    // 65536 u32
                            float* __restrict__ bias){  // 2048
    u32 e = blockIdx.x * blockDim.x + threadIdx.x;      // 0 .. 262143
    {
        float2 v = ((const float2*)Wih)[e];
        wih16u[e] = pack2(v.x, v.y);
    }
    if (e < 196608u){
        u32 l = (e >= 98304u) ? 1u : 0u;
        u32 rem = e - l*98304u;
        u32 pidx = rem >> 10, L = rem & 1023u;
        u32 r = pidx / 24u, p = pidx - r*24u;
        u32 j = L >> 2, q = L & 3u;
        u32 row = r*256u + j;
        u32 P = 32u*q + p;
        float2 v = ((const float2*)Whh)[((size_t)l*1024u + row)*128u + P];
        wreg[e] = pack2(v.x, v.y);
    } else {
        u32 e2 = e - 196608u;                 // 0..65535
        u32 l = e2 >> 15, rem = e2 & 32767u;
        u32 i2 = rem >> 10, L = rem & 1023u;  // i2 = r*8+k
        u32 r = i2 >> 3, k = i2 & 7u;
        u32 j = L >> 2, q = L & 3u;
        u32 row = r*256u + j;
        u32 P = 32u*q + 24u + k;
        float2 v = ((const float2*)Whh)[((size_t)l*1024u + row)*128u + P];
        wldsg[e2] = pack2(v.x, v.y);
    }
    if (e < 2048u){
        u32 l = e >> 10, Ls = e & 1023u;
        u32 src = l*1024u + (((Ls & 3u) << 8) | (Ls >> 2));
        bias[e] = bih[src] + bhh[src];
    }
}

// ---------- per-chunk input convert: fp32 -> fp16 rows [beta][tc][256] ----------
__global__ void cvt_chunk(const float* __restrict__ in1,
                          const float* __restrict__ in2,
                          u16* __restrict__ a16,    // [256*Tc][256] fp16
                          int t0, int lgTc){
    u32 idx = blockIdx.x * blockDim.x + threadIdx.x;   // float4 units
    u32 c4  = idx & 63;
    u32 row = idx >> 6;
    u32 tc   = row & ((1u << lgTc) - 1u);
    u32 beta = row >> lgTc;
    const float* base = (beta < 128u) ? in1 : in2;
    float4 v = *(const float4*)(base + ((size_t)(beta & 127u)*512u + (size_t)(t0 + tc))*256u + c4*4u);
    ((uint2*)a16)[idx] = make_uint2(pack2(v.x, v.y), pack2(v.z, v.w));
}

// ---------- projection GEMM:  C[Mc,1024] = A[Mc,256] * B[1024,256]^T ----------
// Each wg stages its 128-row B tile ONCE, then loops 4 M-tiles (no barriers in
// the loop). grid = (2Tc/4 Mgroups, 8 Ntiles); Mgroups%8==0 -> the 8 N-variants
// of an M-group land on the same XCD (A-panel L2 locality).
// Output columns stored PERMUTED: col n -> slot ((n&255)<<2)|(n>>8).
#define MPW 4
__global__ __launch_bounds__(256) void proj_gemm(
        const u16*  __restrict__ A16,     // [Mc][256] fp16
        const u16*  __restrict__ Bw,      // [1024][256] fp16 = W_ih[l]
        u16*        __restrict__ Cout){   // [Mc][1024] fp16 (permuted cols)
    __shared__ u16 Blds[128][264];        // 528B rows: 16B-aligned for uint4
    const int tid = threadIdx.x;
    const int n0 = blockIdx.y * 128;

    {   // stage B tile: 128 rows x 32 uint4, coalesced 16B loads
        const uint4* src = (const uint4*)Bw;
        #pragma unroll
        for (int i = 0; i < 16; i++){
            int idx = i*256 + tid;          // 0..4095
            int r = idx >> 5, c4 = idx & 31;
            uint4 v = src[(size_t)(n0 + r)*32 + c4];
            *(uint4*)&Blds[r][c4*8] = v;
        }
    }
    __syncthreads();

    const int l   = tid & 63;
    const int wid = tid >> 6;
    const int wm = (wid >> 1) * 64;
    const int wn = (wid & 1) * 64;
    const int lr = l & 15;
    const int lk = l >> 4;

    for (int mt = 0; mt < MPW; mt++){
        const int m0 = (blockIdx.x*MPW + mt) * 128;

        f4v acc[4][4] = {};
        const u16* a16p[4];
        #pragma unroll
        for (int f = 0; f < 4; f++)
            a16p[f] = A16 + (size_t)(m0 + wm + f*16 + lr)*256 + lk*8;

        #pragma unroll
        for (int ks = 0; ks < 8; ks++){
            uint4 a_[4], b_[4];
            #pragma unroll
            for (int f = 0; f < 4; f++)
                a_[f] = *(const uint4*)(a16p[f] + ks*32);
            #pragma unroll
            for (int f = 0; f < 4; f++)
                b_[f] = *(const uint4*)&Blds[wn + f*16 + lr][ks*32 + lk*8];
            #pragma unroll
            for (int fm = 0; fm < 4; fm++)
                #pragma unroll
                for (int fn = 0; fn < 4; fn++)
                    acc[fm][fn] = __builtin_amdgcn_mfma_f32_16x16x32_f16(
                        __builtin_bit_cast(h8v, a_[fm]),
                        __builtin_bit_cast(h8v, b_[fn]),
                        acc[fm][fn], 0, 0, 0);
        }

        // D[row = 4*lk + i][col = lr]; store col n at permuted slot
        #pragma unroll
        for (int fm = 0; fm < 4; fm++){
            #pragma unroll
            for (int i = 0; i < 4; i++){
                int m = m0 + wm + fm*16 + lk*4 + i;
                size_t rowoff = (size_t)m*1024;
                #pragma unroll
                for (int fn = 0; fn < 4; fn++){
                    int n = n0 + wn + fn*16 + lr;
                    int np = ((n & 255) << 2) | (n >> 8);
                    Cout[rowoff + np] = f2h_bits(acc[fm][fn][i]);
                }
            }
        }
    }
}

// ---------- persistent LSTM recurrence over one T-chunk ----------
// (r8 structure - measured 485 us, VALU 74%, 0 conflicts - plus unroll-2 and
// unguarded prefetch; the one-past-end read lands in the adjacent hsc region)
__global__ __launch_bounds__(1024, 4) void lstm_rec(
        const u16* __restrict__ xg,      // [beta][tc][1024] fp16, permuted cols
        const u32* __restrict__ wreg,    // [96][1024] this layer
        const u32* __restrict__ wldsg,   // [32][1024] this layer
        const float* __restrict__ bias,  // [1024] permuted
        u16* __restrict__ hseq,          // [beta][tc][256] chunk, or null
        u16* __restrict__ h_state,       // [256][256] fp16
        float* __restrict__ c_state,     // [256][256] f32
        int Tc, int write_seq, int first){
    __shared__ u32 wlds[1024*36];               // 144 KB, row stride 36 u32
    __shared__ alignas(16) u16 hbufF[2*288];    // 2 bufs x 4 quarters x 72

    const int L    = threadIdx.x;        // slot
    const int q    = L & 3;              // gate / k-quarter
    const int j    = L >> 2;             // h-element index
    const int beta = blockIdx.x;

    u32 w[96];
    #pragma unroll
    for (int t = 0; t < 96; t++)
        w[t] = wreg[(size_t)t*1024 + L];
    #pragma unroll
    for (int i = 0; i < 32; i++)
        wlds[L*36 + i] = wldsg[(size_t)i*1024 + L];

    const float bs = bias[L];
    float c = 0.f;
    u16 hb_last = 0;
    if (q == 0){
        u16 h0 = first ? (u16)0 : h_state[(size_t)beta*256 + j];
        hbufF[72*(j >> 6) + (j & 63)] = h0;
        hb_last = h0;
        if (!first) c = c_state[(size_t)beta*256 + j];
    }
    __syncthreads();

    const u16* xr = xg + (size_t)beta * Tc * 1024 + L;
    u16 xcur = xr[0];
    const uint4* wr = (const uint4*)&wlds[L*36];

    #pragma unroll 2
    for (int tc = 0; tc < Tc; tc++){
        u16 xnext = xr[(size_t)(tc+1)*1024];   // unguarded; lands in hsc at end

        const uint4* hv = (const uint4*)&hbufF[(tc & 1)*288 + 72*q];
        float pA = 0.f, pB = 0.f, pC = 0.f, pD = 0.f;

        #pragma unroll
        for (int i = 0; i < 6; i++){             // pairs 0..23 of each row (regs)
            uint4 hh = hv[i];
            pA = fdot2(w[   4*i+0], hh.x, pA); pA = fdot2(w[   4*i+1], hh.y, pA);
            pA = fdot2(w[   4*i+2], hh.z, pA); pA = fdot2(w[   4*i+3], hh.w, pA);
            pB = fdot2(w[24+4*i+0], hh.x, pB); pB = fdot2(w[24+4*i+1], hh.y, pB);
            pB = fdot2(w[24+4*i+2], hh.z, pB); pB = fdot2(w[24+4*i+3], hh.w, pB);
            pC = fdot2(w[48+4*i+0], hh.x, pC); pC = fdot2(w[48+4*i+1], hh.y, pC);
            pC = fdot2(w[48+4*i+2], hh.z, pC); pC = fdot2(w[48+4*i+3], hh.w, pC);
            pD = fdot2(w[72+4*i+0], hh.x, pD); pD = fdot2(w[72+4*i+1], hh.y, pD);
            pD = fdot2(w[72+4*i+2], hh.z, pD); pD = fdot2(w[72+4*i+3], hh.w, pD);
        }
        #pragma unroll
        for (int m = 0; m < 2; m++){             // pairs 24..31 (LDS)
            uint4 hh = hv[6+m];
            uint4 wa = wr[0+m], wb = wr[2+m], wc = wr[4+m], wd = wr[6+m];
            pA = fdot2(wa.x, hh.x, pA); pA = fdot2(wa.y, hh.y, pA);
            pA = fdot2(wa.z, hh.z, pA); pA = fdot2(wa.w, hh.w, pA);
            pB = fdot2(wb.x, hh.x, pB); pB = fdot2(wb.y, hh.y, pB);
            pB = fdot2(wb.z, hh.z, pB); pB = fdot2(wb.w, hh.w, pB);
            pC = fdot2(wc.x, hh.x, pC); pC = fdot2(wc.y, hh.y, pC);
            pC = fdot2(wc.z, hh.z, pC); pC = fdot2(wc.w, hh.w, pC);
            pD = fdot2(wd.x, hh.x, pD); pD = fdot2(wd.y, hh.y, pD);
            pD = fdot2(wd.z, hh.z, pD); pD = fdot2(wd.w, hh.w, pD);
        }

        // quad transpose-reduce (DPP): thread ends with row q over all quarters
        float k0_ = (q & 1) ? pB : pA;
        float k1_ = (q & 1) ? pD : pC;
        float s0_ = (q & 1) ? pA : pB;
        float s1_ = (q & 1) ? pC : pD;
        k0_ += dpp_qp<0xB1>(s0_);
        k1_ += dpp_qp<0xB1>(s1_);
        float kf = (q & 2) ? k1_ : k0_;
        float sf = (q & 2) ? k0_ : k1_;
        kf += dpp_qp<0x4E>(sf);

        float acc = kf + bs + (float)__builtin_bit_cast(_Float16, xcur);

        // activation: q==2 -> tanh, else sigmoid (one exp per thread)
        float targ = (q == 2) ? 2.f*acc : -acc;
        float e1 = __expf(targ);
        float rr = 1.f / (1.f + e1);
        float a  = (q == 2) ? 1.f - 2.f*rr : rr;

        // gate exchange within quad (DPP): on q==0: a=i p1=f p2=g p3=o
        float p1 = dpp_qp<0xB1>(a);
        float p2 = dpp_qp<0x4E>(a);
        float p3 = dpp_qp<0x4E>(p1);

        c = (q == 0) ? (p1*c + a*p2) : 0.f;
        float e2 = __expf(2.f*c);
        float th = 1.f - 2.f/(e2 + 1.f);
        float h  = p3 * th;
        u16 hb = f2h_bits(h);

        if (q == 0){
            hbufF[((tc & 1)^1)*288 + 72*(j >> 6) + (j & 63)] = hb;
            hb_last = hb;
            if (write_seq) hseq[((size_t)beta*Tc + tc)*256 + j] = hb;
        }
        xcur = xnext;
        __syncthreads();
    }

    if (q == 0){
        h_state[(size_t)beta*256 + j] = hb_last;
        c_state[(size_t)beta*256 + j] = c;
    }
}

// ---------- final FC: out[r][k] = relu(hn[r]) . fc_w[k] + fc_b[k] ----------
__global__ void fc_out(const u16* __restrict__ hlast,
                       const float* __restrict__ fcw,   // [5][256]
                       const float* __restrict__ fcb,   // [5]
                       float* __restrict__ out){        // [512][5]
    int r = blockIdx.x;
    int lane = threadIdx.x;      // 0..63
    int inp = r >> 8, rem = r & 255, l = rem >> 7, b = rem & 127;
    int beta = inp*128 + b;
    const u16* h = hlast + ((size_t)l*256 + beta)*256;

    int j0 = lane * 4;
    uint2 hb = *(const uint2*)(h + j0);
    h2v p0 = __builtin_bit_cast(h2v, hb.x), p1 = __builtin_bit_cast(h2v, hb.y);
    float hv0 = fmaxf((float)p0[0], 0.f);
    float hv1 = fmaxf((float)p0[1], 0.f);
    float hv2 = fmaxf((float)p1[0], 0.f);
    float hv3 = fmaxf((float)p1[1], 0.f);

    float acc[5];
    #pragma unroll
    for (int k = 0; k < 5; k++){
        float4 w = *(const float4*)(fcw + k*256 + j0);
        acc[k] = hv0*w.x + hv1*w.y + hv2*w.z + hv3*w.w;
    }
    #pragma unroll
    for (int k = 0; k < 5; k++)
        #pragma unroll
        for (int off = 32; off > 0; off >>= 1)
            acc[k] += __shfl_xor(acc[k], off);
    if (lane == 0){
        #pragma unroll
        for (int k = 0; k < 5; k++)
            out[(size_t)r*5 + k] = acc[k] + fcb[k];
    }
}

// ---------- host launch ----------
extern "C" void kernel_launch(void* const* d_in, const int* in_sizes, int n_in,
                              void* d_out, int out_size, void* d_ws, size_t ws_size,
                              hipStream_t stream) {
    const float* in1 = (const float*)d_in[0];
    const float* in2 = (const float*)d_in[1];
    const float* Wih = (const float*)d_in[2];
    const float* Whh = (const float*)d_in[3];
    const float* bih = (const float*)d_in[4];
    const float* bhh = (const float*)d_in[5];
    const float* fcw = (const float*)d_in[6];
    const float* fcb = (const float*)d_in[7];
    float* out = (float*)d_out;

    // fixed workspace region (~3 MB)
    char* ws = (char*)d_ws;
    u16*   wih16   = (u16*)  (ws + 0x000000);   // [2][1024][256] fp16 (1 MB)
    u32*   wreg    = (u32*)  (ws + 0x100000);   // [2][96][1024] u32 (768 KB)
    u32*   wldsg   = (u32*)  (ws + 0x1C0000);   // [2][32][1024] u32 (256 KB)
    float* bias    = (float*)(ws + 0x200000);   // [2][1024]
    u16*   h_state = (u16*)  (ws + 0x202000);   // [2][256][256] fp16 (256 KB)
    float* c_state = (float*)(ws + 0x242000);   // [2][256][256] f32  (512 KB)
    const size_t chunk_off = 0x300000;

    // adaptive T-chunk: xg chunk = Tc*512KB, hsc chunk (a16/hseq alias) = Tc*128KB
    int Tc = 8;
    for (int cand = 512; cand >= 8; cand >>= 1){
        if (chunk_off + (size_t)cand * 655360ull <= ws_size){ Tc = cand; break; }
    }
    int lgTc = 31 - __builtin_clz((u32)Tc);
    u16* xgc = (u16*)(ws + chunk_off);
    u16* hsc = (u16*)(ws + chunk_off + (size_t)Tc * 524288ull);  // dual: a16 then hseq

    cvt_weights<<<1024, 256, 0, stream>>>(Wih, Whh, bih, bhh,
                                          (u32*)wih16, wreg, wldsg, bias);

    const int nch = 512 / Tc;
    dim3 pg(2*Tc/MPW, 8);   // x = M-groups (4 M-tiles each), y = N-tiles
    for (int k = 0; k < nch; k++){
        int t0 = k * Tc;
        // convert this chunk's fp32 inputs -> fp16 A (into hsc, dead after proj0)
        cvt_chunk<<<64*Tc, 256, 0, stream>>>(in1, in2, hsc, t0, lgTc);
        // layer 0
        proj_gemm<<<pg, 256, 0, stream>>>(hsc, wih16, xgc);
        lstm_rec<<<256, 1024, 0, stream>>>((const u16*)xgc, wreg, wldsg, bias,
                                           hsc, h_state, c_state,
                                           Tc, 1, k == 0);
        // layer 1
        proj_gemm<<<pg, 256, 0, stream>>>(hsc, wih16 + 262144, xgc);
        lstm_rec<<<256, 1024, 0, stream>>>((const u16*)xgc, wreg + 98304, wldsg + 32768,
                                           bias + 1024,
                                           (u16*)nullptr, h_state + 65536, c_state + 65536,
                                           Tc, 0, k == 0);
    }
    fc_out<<<512, 64, 0, stream>>>(h_state, fcw, fcb, out);
}